// Round 1
// baseline (3028.240 us; speedup 1.0000x reference)
//
#include <hip/hip_runtime.h>
#include <hip/hip_bf16.h>

// Masked self-attention, fp32 baseline (round 1).
// B=16, S=1024 (256 image prefix + 768 text), E=1024.
// Pipeline: [qkv_proj] -> [scores+mask] -> [row softmax] -> [PV].
// Q lives in d_out (64 MB), K/V/scores in d_ws (needs 192 MB).

#define BATCH 16
#define SEQL  1024
#define IMG   256
#define EMB   1024
#define MTOT  (BATCH * SEQL)   // 16384

// ---------------------------------------------------------------------------
// Y = A (M x K) * W^T (N x K, row-major) + bias.  Tile 64x64, BK=16,
// 256 threads, 4x4 accumulator per thread.  blockIdx.z picks Q/K/V.
// ---------------------------------------------------------------------------
__global__ __launch_bounds__(256) void qkv_proj_kernel(
    const float* __restrict__ x,
    const float* __restrict__ Wq, const float* __restrict__ bq,
    const float* __restrict__ Wk, const float* __restrict__ bk,
    const float* __restrict__ Wv, const float* __restrict__ bv,
    float* __restrict__ Qo, float* __restrict__ Ko, float* __restrict__ Vo)
{
    const float* W; const float* bias; float* Y;
    if (blockIdx.z == 0)      { W = Wq; bias = bq; Y = Qo; }
    else if (blockIdx.z == 1) { W = Wk; bias = bk; Y = Ko; }
    else                      { W = Wv; bias = bv; Y = Vo; }

    __shared__ float As[64][17];   // +1 pad breaks power-of-2 bank stride
    __shared__ float Bs[64][17];

    const int tid = threadIdx.x;
    const int tx = tid & 15;       // 0..15  (N direction)
    const int ty = tid >> 4;       // 0..15  (M direction)
    const int m0 = blockIdx.x * 64;
    const int n0 = blockIdx.y * 64;

    const int lrow = tid >> 2;         // 0..63
    const int lc4  = (tid & 3) * 4;    // 0,4,8,12

    float acc[4][4] = {};

    for (int k0 = 0; k0 < EMB; k0 += 16) {
        const float4 av = *reinterpret_cast<const float4*>(
            &x[(size_t)(m0 + lrow) * EMB + k0 + lc4]);
        const float4 wv = *reinterpret_cast<const float4*>(
            &W[(size_t)(n0 + lrow) * EMB + k0 + lc4]);
        As[lrow][lc4 + 0] = av.x; As[lrow][lc4 + 1] = av.y;
        As[lrow][lc4 + 2] = av.z; As[lrow][lc4 + 3] = av.w;
        Bs[lrow][lc4 + 0] = wv.x; Bs[lrow][lc4 + 1] = wv.y;
        Bs[lrow][lc4 + 2] = wv.z; Bs[lrow][lc4 + 3] = wv.w;
        __syncthreads();

        #pragma unroll
        for (int kk = 0; kk < 16; ++kk) {
            float a[4], b[4];
            #pragma unroll
            for (int i = 0; i < 4; ++i) a[i] = As[ty * 4 + i][kk];
            #pragma unroll
            for (int j = 0; j < 4; ++j) b[j] = Bs[tx * 4 + j][kk];
            #pragma unroll
            for (int i = 0; i < 4; ++i)
                #pragma unroll
                for (int j = 0; j < 4; ++j)
                    acc[i][j] += a[i] * b[j];
        }
        __syncthreads();
    }

    #pragma unroll
    for (int i = 0; i < 4; ++i) {
        const size_t row = (size_t)(m0 + ty * 4 + i);
        #pragma unroll
        for (int j = 0; j < 4; ++j) {
            const int col = n0 + tx * 4 + j;
            Y[row * EMB + col] = acc[i][j] + bias[col];
        }
    }
}

// ---------------------------------------------------------------------------
// scores[b,q,k] = (Q[b,q,:] . K[b,k,:]) / 32, masked to -1e9 where
// (k >= IMG && k > q).  Fully-masked 64x64 tiles are skipped (no GEMM).
// blockIdx: x = q-tile, y = k-tile, z = batch.
// ---------------------------------------------------------------------------
__global__ __launch_bounds__(256) void scores_kernel(
    const float* __restrict__ Q, const float* __restrict__ K,
    float* __restrict__ sims)
{
    const int b  = blockIdx.z;
    const int m0 = blockIdx.x * 64;   // q offset
    const int n0 = blockIdx.y * 64;   // k offset

    const float* Qb = Q + (size_t)b * SEQL * EMB;
    const float* Kb = K + (size_t)b * SEQL * EMB;
    float* Sb = sims + (size_t)b * SEQL * SEQL;

    const int tid = threadIdx.x;
    const int tx = tid & 15;
    const int ty = tid >> 4;

    // fully masked tile: every k in tile >= IMG and > every q in tile
    if (n0 >= IMG && n0 > m0 + 63) {
        #pragma unroll
        for (int i = 0; i < 4; ++i) {
            const int q = m0 + ty * 4 + i;
            #pragma unroll
            for (int j = 0; j < 4; ++j)
                Sb[(size_t)q * SEQL + n0 + tx * 4 + j] = -1e9f;
        }
        return;
    }

    __shared__ float As[64][17];
    __shared__ float Bs[64][17];
    const int lrow = tid >> 2;
    const int lc4  = (tid & 3) * 4;

    float acc[4][4] = {};

    for (int k0 = 0; k0 < EMB; k0 += 16) {
        const float4 av = *reinterpret_cast<const float4*>(
            &Qb[(size_t)(m0 + lrow) * EMB + k0 + lc4]);
        const float4 kv = *reinterpret_cast<const float4*>(
            &Kb[(size_t)(n0 + lrow) * EMB + k0 + lc4]);
        As[lrow][lc4 + 0] = av.x; As[lrow][lc4 + 1] = av.y;
        As[lrow][lc4 + 2] = av.z; As[lrow][lc4 + 3] = av.w;
        Bs[lrow][lc4 + 0] = kv.x; Bs[lrow][lc4 + 1] = kv.y;
        Bs[lrow][lc4 + 2] = kv.z; Bs[lrow][lc4 + 3] = kv.w;
        __syncthreads();

        #pragma unroll
        for (int kk = 0; kk < 16; ++kk) {
            float a[4], bb[4];
            #pragma unroll
            for (int i = 0; i < 4; ++i) a[i] = As[ty * 4 + i][kk];
            #pragma unroll
            for (int j = 0; j < 4; ++j) bb[j] = Bs[tx * 4 + j][kk];
            #pragma unroll
            for (int i = 0; i < 4; ++i)
                #pragma unroll
                for (int j = 0; j < 4; ++j)
                    acc[i][j] += a[i] * bb[j];
        }
        __syncthreads();
    }

    #pragma unroll
    for (int i = 0; i < 4; ++i) {
        const int q = m0 + ty * 4 + i;
        #pragma unroll
        for (int j = 0; j < 4; ++j) {
            const int k = n0 + tx * 4 + j;
            float v = acc[i][j] * 0.03125f;             // 1/sqrt(1024)
            if (k >= IMG && k > q) v = -1e9f;
            Sb[(size_t)q * SEQL + k] = v;
        }
    }
}

// ---------------------------------------------------------------------------
// In-place row softmax over 1024 entries. One block (256 thr) per row,
// one float4 per thread.
// ---------------------------------------------------------------------------
__global__ __launch_bounds__(256) void softmax_kernel(float* __restrict__ sims)
{
    float* p = sims + (size_t)blockIdx.x * SEQL;
    const int tid = threadIdx.x;
    float4 v = reinterpret_cast<float4*>(p)[tid];

    __shared__ float red[8];

    float m = fmaxf(fmaxf(v.x, v.y), fmaxf(v.z, v.w));
    #pragma unroll
    for (int off = 32; off > 0; off >>= 1) m = fmaxf(m, __shfl_xor(m, off));
    if ((tid & 63) == 0) red[tid >> 6] = m;
    __syncthreads();
    m = fmaxf(fmaxf(red[0], red[1]), fmaxf(red[2], red[3]));

    float4 e;
    e.x = __expf(v.x - m); e.y = __expf(v.y - m);
    e.z = __expf(v.z - m); e.w = __expf(v.w - m);
    float s = e.x + e.y + e.z + e.w;
    #pragma unroll
    for (int off = 32; off > 0; off >>= 1) s += __shfl_xor(s, off);
    if ((tid & 63) == 0) red[4 + (tid >> 6)] = s;
    __syncthreads();
    s = red[4] + red[5] + red[6] + red[7];

    const float inv = 1.0f / s;
    e.x *= inv; e.y *= inv; e.z *= inv; e.w *= inv;
    reinterpret_cast<float4*>(p)[tid] = e;
}

// ---------------------------------------------------------------------------
// out[b,q,d] = sum_k attn[b,q,k] * V[b,k,d].  A row-major [S,S],
// B row-major [S,E] (not transposed).  K-loop truncated to the unmasked
// range max(IMG, q0+64) per q-tile (attn is exactly 0 beyond it).
// ---------------------------------------------------------------------------
__global__ __launch_bounds__(256) void pv_kernel(
    const float* __restrict__ attn, const float* __restrict__ V,
    float* __restrict__ out)
{
    const int b  = blockIdx.z;
    const int m0 = blockIdx.x * 64;   // q offset
    const int n0 = blockIdx.y * 64;   // d offset

    const float* Ab = attn + (size_t)b * SEQL * SEQL;
    const float* Vb = V + (size_t)b * SEQL * EMB;
    float* Ob = out + (size_t)b * SEQL * EMB;

    const int tid = threadIdx.x;
    const int tx = tid & 15;
    const int ty = tid >> 4;

    __shared__ float As[64][17];   // attn tile [64 q][16 k]
    __shared__ float Bs[16][68];   // V tile [16 k][64 d], padded, 16B-aligned rows

    const int lrow = tid >> 2;          // 0..63 (for A)
    const int lc4  = (tid & 3) * 4;
    const int br   = tid >> 4;          // 0..15 (for B)
    const int bc4  = (tid & 15) * 4;

    float acc[4][4] = {};
    const int kmax = (IMG > m0 + 64) ? IMG : (m0 + 64);

    for (int k0 = 0; k0 < kmax; k0 += 16) {
        const float4 av = *reinterpret_cast<const float4*>(
            &Ab[(size_t)(m0 + lrow) * SEQL + k0 + lc4]);
        const float4 bv = *reinterpret_cast<const float4*>(
            &Vb[(size_t)(k0 + br) * EMB + n0 + bc4]);
        As[lrow][lc4 + 0] = av.x; As[lrow][lc4 + 1] = av.y;
        As[lrow][lc4 + 2] = av.z; As[lrow][lc4 + 3] = av.w;
        *reinterpret_cast<float4*>(&Bs[br][bc4]) = bv;
        __syncthreads();

        #pragma unroll
        for (int kk = 0; kk < 16; ++kk) {
            float a[4], bb[4];
            #pragma unroll
            for (int i = 0; i < 4; ++i) a[i] = As[ty * 4 + i][kk];
            #pragma unroll
            for (int j = 0; j < 4; ++j) bb[j] = Bs[kk][tx * 4 + j];
            #pragma unroll
            for (int i = 0; i < 4; ++i)
                #pragma unroll
                for (int j = 0; j < 4; ++j)
                    acc[i][j] += a[i] * bb[j];
        }
        __syncthreads();
    }

    #pragma unroll
    for (int i = 0; i < 4; ++i) {
        const size_t q = (size_t)(m0 + ty * 4 + i);
        #pragma unroll
        for (int j = 0; j < 4; ++j)
            Ob[q * EMB + n0 + tx * 4 + j] = acc[i][j];
    }
}

// ---------------------------------------------------------------------------
extern "C" void kernel_launch(void* const* d_in, const int* in_sizes, int n_in,
                              void* d_out, int out_size, void* d_ws, size_t ws_size,
                              hipStream_t stream)
{
    const float* x  = (const float*)d_in[0];
    const float* Wq = (const float*)d_in[1];
    const float* bq = (const float*)d_in[2];
    const float* Wk = (const float*)d_in[3];
    const float* bk = (const float*)d_in[4];
    const float* Wv = (const float*)d_in[5];
    const float* bv = (const float*)d_in[6];

    float* Qbuf = (float*)d_out;                       // 64 MB, overwritten by pv
    float* Kbuf = (float*)d_ws;                        // 64 MB
    float* Vbuf = Kbuf + (size_t)MTOT * EMB;           // 64 MB
    float* sims = Vbuf + (size_t)MTOT * EMB;           // 64 MB

    qkv_proj_kernel<<<dim3(MTOT / 64, EMB / 64, 3), 256, 0, stream>>>(
        x, Wq, bq, Wk, bk, Wv, bv, Qbuf, Kbuf, Vbuf);

    scores_kernel<<<dim3(SEQL / 64, SEQL / 64, BATCH), 256, 0, stream>>>(
        Qbuf, Kbuf, sims);

    softmax_kernel<<<dim3(BATCH * SEQL), 256, 0, stream>>>(sims);

    pv_kernel<<<dim3(SEQL / 64, EMB / 64, BATCH), 256, 0, stream>>>(
        sims, Vbuf, (float*)d_out);
}

// Round 2
// 298.549 us; speedup vs baseline: 10.1432x; 10.1432x over previous
//
#include <hip/hip_runtime.h>
#include <hip/hip_bf16.h>
#include <stdint.h>

// Masked self-attention, full bf16-MFMA pipeline (round 2).
// B=16, S=1024 (256 image prefix), E=1024.
// convert(x,W->bf16) -> qkv MFMA (Q,K bf16; V transposed bf16)
//   -> scores MFMA (tile-skip, fp32 in d_out) -> softmax (fp32 math, bf16 out)
//   -> PV MFMA (K-truncated, fp32 out).
// ws layout (bf16 elems): [Qb NE][Kb NE][Vtb NE][Xb NE | attnb NE][Wb 3M]
//   NE = 16*1024*1024; total 140.5 MB (<= 192 MB proven in round 1).

#define BATCH 16
#define SEQL  1024
#define IMG   256
#define EMB   1024
#define MTOT  (BATCH * SEQL)   // 16384

typedef __attribute__((ext_vector_type(8))) short short8;
typedef __attribute__((ext_vector_type(8))) unsigned short u16x8;
typedef __attribute__((ext_vector_type(4))) unsigned short u16x4;
typedef __attribute__((ext_vector_type(4))) float f32x4;

// ---------------------------------------------------------------------------
// async global->LDS, 16 B per lane; LDS dest is wave-uniform base + lane*16.
// ---------------------------------------------------------------------------
__device__ __forceinline__ void gload_lds16(const void* g, void* l) {
    __builtin_amdgcn_global_load_lds(
        (const __attribute__((address_space(1))) void*)g,
        (__attribute__((address_space(3))) void*)l, 16, 0, 0);
}

// round-to-nearest-even f32 -> bf16 bits (finite inputs only)
__device__ __forceinline__ unsigned short f2bf(float f) {
    uint32_t u = __float_as_uint(f);
    u += 0x7FFFu + ((u >> 16) & 1u);
    return (unsigned short)(u >> 16);
}

// ---------------------------------------------------------------------------
// Core: 128x128 output tile, C = A (128 x 32k) * B^T, both operands row-major
// with row stride 1024 bf16 (2048 B). 256 threads = 4 waves in 2x2, each wave
// a 64x64 sub-tile as 4x4 mfma_f32_16x16x32_bf16 fragments. m97 2-barrier loop.
// ---------------------------------------------------------------------------
__device__ __forceinline__ void mfma_core128(
    const unsigned short* __restrict__ Aa,   // tile base: rows m0.., k from 0
    const unsigned short* __restrict__ Bb,   // tile base: rows n0.., k from 0
    char* AsB, char* BsB, int kSteps, f32x4 acc[4][4])
{
    const int tid  = threadIdx.x;
    const int lane = tid & 63;
    const int wv   = tid >> 6;
    const int wr   = wv >> 1, wc = wv & 1;

    // staging: tile is 128 rows x 64 B, linear in LDS. chunk = wv (+4), each
    // chunk = 1024 B = one wave-call of 64 lanes x 16 B.
    const int srow = wv * 16 + (lane >> 2);      // 0..63
    const int skb  = (lane & 3) * 16;            // byte offset in 64 B row

    const char* aS0 = (const char*)Aa + (size_t)srow * 2048 + skb;
    const char* aS1 = aS0 + 64 * 2048;
    const char* bS0 = (const char*)Bb + (size_t)srow * 2048 + skb;
    const char* bS1 = bS0 + 64 * 2048;
    char* aD0 = AsB + wv * 1024;  char* aD1 = aD0 + 4096;
    char* bD0 = BsB + wv * 1024;  char* bD1 = bD0 + 4096;

    // fragment reads: lane = row(lr) + 16*kgroup(kh), 8 bf16 contiguous k
    const int lr = lane & 15, kh = lane >> 4;
    const char* aRd = AsB + (wr * 64 + lr) * 64 + kh * 16;
    const char* bRd = BsB + (wc * 64 + lr) * 64 + kh * 16;

    for (int ks = 0; ks < kSteps; ++ks) {
        gload_lds16(aS0, aD0);
        gload_lds16(aS1, aD1);
        gload_lds16(bS0, bD0);
        gload_lds16(bS1, bD1);
        aS0 += 64; aS1 += 64; bS0 += 64; bS1 += 64;
        __syncthreads();   // drains vmcnt(0) before barrier (compiler-enforced)

        short8 af[4], bfr[4];
        #pragma unroll
        for (int i = 0; i < 4; ++i) af[i]  = *(const short8*)(aRd + i * 1024);
        #pragma unroll
        for (int j = 0; j < 4; ++j) bfr[j] = *(const short8*)(bRd + j * 1024);
        #pragma unroll
        for (int i = 0; i < 4; ++i)
            #pragma unroll
            for (int j = 0; j < 4; ++j)
                acc[i][j] = __builtin_amdgcn_mfma_f32_16x16x32_bf16(
                    af[i], bfr[j], acc[i][j], 0, 0, 0);
        __syncthreads();   // protect LDS before next stage
    }
}

// ---------------------------------------------------------------------------
// fp32 -> bf16 conversion of x and the three weight matrices.
// ---------------------------------------------------------------------------
__global__ __launch_bounds__(256) void convert_bf16(
    const float* __restrict__ x,
    const float* __restrict__ Wq, const float* __restrict__ Wk,
    const float* __restrict__ Wv,
    unsigned short* __restrict__ Xb, unsigned short* __restrict__ Wb)
{
    const size_t NE  = (size_t)MTOT * EMB;
    const size_t idx = ((size_t)blockIdx.x * 256 + threadIdx.x) * 8;
    const float* src; unsigned short* dst; size_t off;
    if (idx < NE) { src = x; dst = Xb; off = idx; }
    else {
        const size_t w = idx - NE;
        const int wi = (int)(w >> 20);
        off = w & 0xFFFFFu;
        src = (wi == 0) ? Wq : (wi == 1) ? Wk : Wv;
        dst = Wb + ((size_t)wi << 20);
    }
    const float4 a = *(const float4*)(src + off);
    const float4 b = *(const float4*)(src + off + 4);
    u16x8 o;
    o[0] = f2bf(a.x); o[1] = f2bf(a.y); o[2] = f2bf(a.z); o[3] = f2bf(a.w);
    o[4] = f2bf(b.x); o[5] = f2bf(b.y); o[6] = f2bf(b.z); o[7] = f2bf(b.w);
    *(u16x8*)(dst + off) = o;
}

// ---------------------------------------------------------------------------
// QKV projection: Y = Xb * W^T + bias. z=0 -> Qb, z=1 -> Kb (both [M][E] bf16),
// z=2 -> Vtb transposed per batch: [b][d][s] bf16 (so PV is a B^T GEMM).
// ---------------------------------------------------------------------------
__global__ __launch_bounds__(256) void qkv_mfma(
    const unsigned short* __restrict__ Xb, const unsigned short* __restrict__ Wb,
    const float* __restrict__ bq, const float* __restrict__ bk,
    const float* __restrict__ bv,
    unsigned short* __restrict__ Qb, unsigned short* __restrict__ Kb,
    unsigned short* __restrict__ Vtb)
{
    __shared__ __align__(16) char smem[16384];
    const int z  = blockIdx.z;
    const int m0 = blockIdx.x * 128, n0 = blockIdx.y * 128;

    const unsigned short* A = Xb + (size_t)m0 * EMB;
    const unsigned short* B = Wb + ((size_t)z << 20) + (size_t)n0 * EMB;
    f32x4 acc[4][4] = {};
    mfma_core128(A, B, smem, smem + 8192, EMB / 32, acc);

    const float* bias = (z == 0) ? bq : (z == 1) ? bk : bv;
    unsigned short* Y = (z == 0) ? Qb : Kb;
    const int tid = threadIdx.x, lane = tid & 63, wv = tid >> 6;
    const int wr = wv >> 1, wc = wv & 1, lr = lane & 15, kh = lane >> 4;

    #pragma unroll
    for (int i = 0; i < 4; ++i) {
        #pragma unroll
        for (int j = 0; j < 4; ++j) {
            const int gcol = n0 + wc * 64 + j * 16 + lr;
            const float bb = bias[gcol];
            #pragma unroll
            for (int r = 0; r < 4; ++r) {
                const int grow = m0 + wr * 64 + i * 16 + kh * 4 + r;
                const float v = acc[i][j][r] + bb;
                if (z < 2) {
                    Y[(size_t)grow * EMB + gcol] = f2bf(v);
                } else {
                    // Vt[b][d=gcol][s=grow&1023]
                    const size_t off = ((size_t)(grow >> 10) << 20)
                                     | ((size_t)gcol << 10)
                                     | (size_t)(grow & 1023);
                    Vtb[off] = f2bf(v);
                }
            }
        }
    }
}

// ---------------------------------------------------------------------------
// scores[b,q,k] = (Q.K)/32, fp32. Fully-masked 128-tiles (j>=2 && j>i) skipped;
// partially-masked entries are computed but never read by softmax.
// ---------------------------------------------------------------------------
__global__ __launch_bounds__(256) void scores_mfma(
    const unsigned short* __restrict__ Qb, const unsigned short* __restrict__ Kb,
    float* __restrict__ sims)
{
    const int ti = blockIdx.x, tj = blockIdx.y, b = blockIdx.z;
    if (tj >= 2 && tj > ti) return;
    __shared__ __align__(16) char smem[16384];

    const size_t boff = (size_t)b << 20;
    const int m0 = ti * 128, n0 = tj * 128;
    const unsigned short* A = Qb + boff + (size_t)m0 * EMB;
    const unsigned short* B = Kb + boff + (size_t)n0 * EMB;
    f32x4 acc[4][4] = {};
    mfma_core128(A, B, smem, smem + 8192, EMB / 32, acc);

    float* S = sims + boff;
    const int tid = threadIdx.x, lane = tid & 63, wv = tid >> 6;
    const int wr = wv >> 1, wc = wv & 1, lr = lane & 15, kh = lane >> 4;
    #pragma unroll
    for (int i = 0; i < 4; ++i)
        #pragma unroll
        for (int j = 0; j < 4; ++j) {
            const int gcol = n0 + wc * 64 + j * 16 + lr;
            #pragma unroll
            for (int r = 0; r < 4; ++r) {
                const int grow = m0 + wr * 64 + i * 16 + kh * 4 + r;
                S[(size_t)grow * SEQL + gcol] = acc[i][j][r] * 0.03125f;
            }
        }
}

// ---------------------------------------------------------------------------
// Row softmax over valid prefix L = max(256, s+1); fp32 math; bf16 output
// zero-padded to Kt = max(256, (s/128+1)*128) so PV's truncated K-loop reads
// only defined data. One 256-thread block per row.
// ---------------------------------------------------------------------------
__global__ __launch_bounds__(256) void softmax_bf16(
    const float* __restrict__ sims, unsigned short* __restrict__ attnb)
{
    const int row = blockIdx.x;                 // 0..16383
    const int s   = row & (SEQL - 1);
    const int L   = (s + 1 > IMG) ? (s + 1) : IMG;
    const int Kt  = ((((s >> 7) + 1) << 7) > IMG) ? (((s >> 7) + 1) << 7) : IMG;

    const float* p = sims + (size_t)row * SEQL;
    const int tid = threadIdx.x, lane = tid & 63, wv = tid >> 6;
    const int c = tid * 4;
    const float4 v = *(const float4*)(p + c);

    __shared__ float red[8];

    float m = -3.0e38f;
    if (c + 0 < L) m = fmaxf(m, v.x);
    if (c + 1 < L) m = fmaxf(m, v.y);
    if (c + 2 < L) m = fmaxf(m, v.z);
    if (c + 3 < L) m = fmaxf(m, v.w);
    #pragma unroll
    for (int off = 32; off > 0; off >>= 1) m = fmaxf(m, __shfl_xor(m, off));
    if (lane == 0) red[wv] = m;
    __syncthreads();
    m = fmaxf(fmaxf(red[0], red[1]), fmaxf(red[2], red[3]));

    const float e0 = (c + 0 < L) ? __expf(v.x - m) : 0.0f;
    const float e1 = (c + 1 < L) ? __expf(v.y - m) : 0.0f;
    const float e2 = (c + 2 < L) ? __expf(v.z - m) : 0.0f;
    const float e3 = (c + 3 < L) ? __expf(v.w - m) : 0.0f;
    float ssum = e0 + e1 + e2 + e3;
    #pragma unroll
    for (int off = 32; off > 0; off >>= 1) ssum += __shfl_xor(ssum, off);
    if (lane == 0) red[4 + wv] = ssum;
    __syncthreads();
    const float inv = 1.0f / (red[4] + red[5] + red[6] + red[7]);

    if (c < Kt) {
        u16x4 o;
        o[0] = f2bf(e0 * inv); o[1] = f2bf(e1 * inv);
        o[2] = f2bf(e2 * inv); o[3] = f2bf(e3 * inv);
        *(u16x4*)(attnb + (size_t)row * SEQL + c) = o;
    }
}

// ---------------------------------------------------------------------------
// out[b,q,d] = attn[b,q,:] . V[b,:,d] via B^T GEMM against Vt[b][d][k].
// K-loop truncated to kmax = max(256, m0+128).
// ---------------------------------------------------------------------------
__global__ __launch_bounds__(256) void pv_mfma(
    const unsigned short* __restrict__ attnb, const unsigned short* __restrict__ Vtb,
    float* __restrict__ out)
{
    const int ti = blockIdx.x, tj = blockIdx.y, b = blockIdx.z;
    __shared__ __align__(16) char smem[16384];

    const size_t boff = (size_t)b << 20;
    const int m0 = ti * 128, n0 = tj * 128;
    const int kmax = (m0 + 128 > IMG) ? (m0 + 128) : IMG;

    const unsigned short* A = attnb + boff + (size_t)m0 * SEQL;
    const unsigned short* B = Vtb + boff + (size_t)n0 * SEQL;
    f32x4 acc[4][4] = {};
    mfma_core128(A, B, smem, smem + 8192, kmax >> 5, acc);

    float* O = out + boff;
    const int tid = threadIdx.x, lane = tid & 63, wv = tid >> 6;
    const int wr = wv >> 1, wc = wv & 1, lr = lane & 15, kh = lane >> 4;
    #pragma unroll
    for (int i = 0; i < 4; ++i)
        #pragma unroll
        for (int j = 0; j < 4; ++j) {
            const int gcol = n0 + wc * 64 + j * 16 + lr;
            #pragma unroll
            for (int r = 0; r < 4; ++r) {
                const int grow = m0 + wr * 64 + i * 16 + kh * 4 + r;
                O[(size_t)grow * EMB + gcol] = acc[i][j][r];
            }
        }
}

// ---------------------------------------------------------------------------
extern "C" void kernel_launch(void* const* d_in, const int* in_sizes, int n_in,
                              void* d_out, int out_size, void* d_ws, size_t ws_size,
                              hipStream_t stream)
{
    const float* x  = (const float*)d_in[0];
    const float* Wq = (const float*)d_in[1];
    const float* bq = (const float*)d_in[2];
    const float* Wk = (const float*)d_in[3];
    const float* bk = (const float*)d_in[4];
    const float* Wv = (const float*)d_in[5];
    const float* bv = (const float*)d_in[6];

    const size_t NE = (size_t)MTOT * EMB;          // 16,777,216
    unsigned short* base  = (unsigned short*)d_ws;
    unsigned short* Qb    = base;                  // NE bf16
    unsigned short* Kb    = base + NE;             // NE
    unsigned short* Vtb   = base + 2 * NE;         // NE
    unsigned short* Xb    = base + 3 * NE;         // NE (dead after qkv)
    unsigned short* attnb = base + 3 * NE;         // reuses Xb region
    unsigned short* Wb    = base + 4 * NE;         // 3*2^20
    float* sims = (float*)d_out;                   // scores scratch, then out

    convert_bf16<<<dim3((unsigned)((NE + 3u * (1u << 20)) / 2048)), 256, 0, stream>>>(
        x, Wq, Wk, Wv, Xb, Wb);

    qkv_mfma<<<dim3(MTOT / 128, EMB / 128, 3), 256, 0, stream>>>(
        Xb, Wb, bq, bk, bv, Qb, Kb, Vtb);

    scores_mfma<<<dim3(8, 8, BATCH), 256, 0, stream>>>(Qb, Kb, sims);

    softmax_bf16<<<dim3(MTOT), 256, 0, stream>>>(sims, attnb);

    pv_mfma<<<dim3(8, 8, BATCH), 256, 0, stream>>>(attnb, Vtb, (float*)d_out);
}

// Round 3
// 265.132 us; speedup vs baseline: 11.4216x; 1.1260x over previous
//
#include <hip/hip_runtime.h>
#include <hip/hip_bf16.h>
#include <stdint.h>

// Masked self-attention (round 3).
// qkv projection moved to the 256^2 8-phase MFMA template (T2+T3+T4+T5):
//   - BK=64, 8 waves (2M x 4N), 128 KiB LDS double-buffered, counted vmcnt(2)
//   - XOR-swizzled LDS (pre-swizzled global_load_lds source + swizzled ds_read)
//   - raw s_barrier (no vmcnt drain), setprio around MFMA clusters
//   - swapped-operand MFMA for Q/K -> packed row-major bf16 stores
// scores/softmax/pv kept from the verified round-2 pipeline.

#define BATCH 16
#define SEQL  1024
#define IMG   256
#define EMB   1024
#define MTOT  (BATCH * SEQL)   // 16384

typedef __attribute__((ext_vector_type(8))) short short8;
typedef __attribute__((ext_vector_type(8))) unsigned short u16x8;
typedef __attribute__((ext_vector_type(4))) unsigned short u16x4;
typedef __attribute__((ext_vector_type(4))) float f32x4;

__device__ __forceinline__ void gload_lds16(const void* g, void* l) {
    __builtin_amdgcn_global_load_lds(
        (const __attribute__((address_space(1))) void*)g,
        (__attribute__((address_space(3))) void*)l, 16, 0, 0);
}

__device__ __forceinline__ unsigned short f2bf(float f) {
    uint32_t u = __float_as_uint(f);
    u += 0x7FFFu + ((u >> 16) & 1u);
    return (unsigned short)(u >> 16);
}

// ===========================================================================
// 8-phase 256x256 GEMM core.  C = A(256 x 64*KT) * B^T, A/B row-major with
// row stride 2048 B (1024 bf16).  8 waves: wr=wv>>2 (2 M-halves of 128),
// wc=wv&3 (4 N-strips of 64).  acc[8][4] f32x4 per thread (128x64 per wave).
// LDS 128 KiB: d*65536 + {A:0 | B:32768} + half*16384.
// Swizzle: colbyte ^= (row&7)<<4, applied to gload SOURCE and ds_read addr.
// SWAP=true computes C^T fragments (mfma(b,a)) for row-contiguous stores.
// ===========================================================================
template<bool SWAP>
__device__ __forceinline__ void gemm8_core(
    const char* __restrict__ Ab, const char* __restrict__ Bb,
    char* lds, const int KT, f32x4 acc[8][4])
{
    const int tid  = threadIdx.x;
    const int lane = tid & 63;
    const int wv   = tid >> 6;
    const int wr   = wv >> 2, wc = wv & 3;
    const int lr   = lane & 15, kh = lane >> 4;

    // ds_read swizzled column-byte offsets for kk=0,1
    const int sw  = (lr & 7) << 4;
    const int cb0 = (kh * 16) ^ sw;
    const int cb1 = (64 + kh * 16) ^ sw;

    // staging: chunk ch = wv*2+c covers rows ch*8+(lane>>3) of a 128-row half;
    // source column pre-swizzled so linear LDS + swizzled read is an identity.
    const size_t psStage = (size_t)(wv * 16 + (lane >> 3)) * 2048
                         + (size_t)((((lane & 7) ^ (lane >> 3))) << 4);

    auto stageA = [&](int tt, int h) {
        if (tt < KT) {
            const char* s = Ab + psStage + (size_t)h * 262144 + (size_t)tt * 128;
            char* d = lds + (tt & 1) * 65536 + h * 16384 + wv * 2048;
            gload_lds16(s, d);
            gload_lds16(s + 16384, d + 1024);
        }
    };
    auto stageB = [&](int tt, int h) {
        if (tt < KT) {
            const char* s = Bb + psStage + (size_t)h * 262144 + (size_t)tt * 128;
            char* d = lds + (tt & 1) * 65536 + 32768 + h * 16384 + wv * 2048;
            gload_lds16(s, d);
            gload_lds16(s + 16384, d + 1024);
        }
    };

    // prologue: tile0 (A0,A1,B0,B1) + A0(1); wait until tile0 resident.
    stageA(0, 0); stageA(0, 1); stageB(0, 0); stageB(0, 1); stageA(1, 0);
    asm volatile("s_waitcnt vmcnt(2)" ::: "memory");
    __builtin_amdgcn_s_barrier();

    short8 af[4][2];   // current iq half: 4 i x 2 kk
    short8 bf[4][2];   // all 4 j x 2 kk

    const int bh   = wc >> 1;
    const int brow = (wc & 1) * 64 + lr;

    #pragma unroll 1
    for (int t = 0; t < KT; ++t) {
        const int d = t & 1;
        const char* aBase = lds + d * 65536 + wr * 16384 + lr * 128;
        const char* bBase = lds + d * 65536 + 32768 + bh * 16384 + brow * 128;

        auto loadA = [&](int IQ) {
            #pragma unroll
            for (int ii = 0; ii < 4; ++ii) {
                af[ii][0] = *(const short8*)(aBase + (IQ * 4 + ii) * 2048 + cb0);
                af[ii][1] = *(const short8*)(aBase + (IQ * 4 + ii) * 2048 + cb1);
            }
        };
        auto loadB = [&](int JQ) {
            #pragma unroll
            for (int jj = 0; jj < 2; ++jj) {
                bf[JQ * 2 + jj][0] = *(const short8*)(bBase + (JQ * 2 + jj) * 2048 + cb0);
                bf[JQ * 2 + jj][1] = *(const short8*)(bBase + (JQ * 2 + jj) * 2048 + cb1);
            }
        };
        auto mfma16 = [&](int IQ, int JQ) {
            __builtin_amdgcn_s_barrier();
            __builtin_amdgcn_s_setprio(1);
            #pragma unroll
            for (int ii = 0; ii < 4; ++ii)
                #pragma unroll
                for (int jj = 0; jj < 2; ++jj)
                    #pragma unroll
                    for (int kk = 0; kk < 2; ++kk) {
                        f32x4& c = acc[IQ * 4 + ii][JQ * 2 + jj];
                        if (SWAP)
                            c = __builtin_amdgcn_mfma_f32_16x16x32_bf16(
                                bf[JQ * 2 + jj][kk], af[ii][kk], c, 0, 0, 0);
                        else
                            c = __builtin_amdgcn_mfma_f32_16x16x32_bf16(
                                af[ii][kk], bf[JQ * 2 + jj][kk], c, 0, 0, 0);
                    }
            __builtin_amdgcn_s_setprio(0);
        };

        // p0: A-frags iq0, B-frags jq0; stage A1(t+1)
        loadA(0); loadB(0); stageA(t + 1, 1);
        mfma16(0, 0);
        __builtin_amdgcn_s_barrier();
        // p1: B-frags jq1; stage B0(t+1)
        loadB(1); stageB(t + 1, 0);
        mfma16(0, 1);
        __builtin_amdgcn_s_barrier();
        // p2: A-frags iq1; stage B1(t+1)
        loadA(1); stageB(t + 1, 1);
        mfma16(1, 1);
        __builtin_amdgcn_s_barrier();
        // p3: no ds loads; stage A0(t+2)
        stageA(t + 2, 0);
        mfma16(1, 0);
        if (t < KT - 2) asm volatile("s_waitcnt vmcnt(2)" ::: "memory");
        else            asm volatile("s_waitcnt vmcnt(0)" ::: "memory");
        __builtin_amdgcn_s_barrier();
    }
}

// Q/K projection: Y = Xb * W^T + bias, bf16 row-major out. SWAP layout ->
// lane&15 = row, (lane>>4)*4+r = 4 consecutive cols -> packed 8 B stores.
__global__ void __launch_bounds__(512, 2) qk_8phase(
    const unsigned short* __restrict__ Xb, const unsigned short* __restrict__ Wb,
    const float* __restrict__ bq, const float* __restrict__ bk,
    unsigned short* __restrict__ Qb, unsigned short* __restrict__ Kb)
{
    extern __shared__ char lds[];
    const int m0 = blockIdx.x * 256, n0 = blockIdx.y * 256, z = blockIdx.z;
    const char* Ab = (const char*)Xb + (size_t)m0 * 2048;
    const char* Bb = (const char*)(Wb + ((size_t)z << 20)) + (size_t)n0 * 2048;

    f32x4 acc[8][4] = {};
    gemm8_core<true>(Ab, Bb, lds, 16, acc);

    unsigned short* Y = z ? Kb : Qb;
    const float* bias = z ? bk : bq;
    const int lane = threadIdx.x & 63, wv = threadIdx.x >> 6;
    const int wr = wv >> 2, wc = wv & 3, lr = lane & 15, kh = lane >> 4;

    #pragma unroll
    for (int i = 0; i < 8; ++i) {
        const int grow = m0 + wr * 128 + i * 16 + lr;
        #pragma unroll
        for (int j = 0; j < 4; ++j) {
            const int gc0 = n0 + wc * 64 + j * 16 + kh * 4;
            const float4 bb = *(const float4*)(bias + gc0);
            u16x4 o;
            o[0] = f2bf(acc[i][j][0] + bb.x);
            o[1] = f2bf(acc[i][j][1] + bb.y);
            o[2] = f2bf(acc[i][j][2] + bb.z);
            o[3] = f2bf(acc[i][j][3] + bb.w);
            *(u16x4*)(Y + (size_t)grow * EMB + gc0) = o;
        }
    }
}

// V projection, stored transposed per batch: Vt[b][d][s] bf16. Non-SWAP ->
// (lane>>4)*4+r = 4 consecutive rows (= s of Vt row d) -> packed 8 B stores.
__global__ void __launch_bounds__(512, 2) v_8phase(
    const unsigned short* __restrict__ Xb, const unsigned short* __restrict__ Wb,
    const float* __restrict__ bv, unsigned short* __restrict__ Vtb)
{
    extern __shared__ char lds[];
    const int m0 = blockIdx.x * 256, n0 = blockIdx.y * 256;
    const char* Ab = (const char*)Xb + (size_t)m0 * 2048;
    const char* Bb = (const char*)(Wb + ((size_t)2 << 20)) + (size_t)n0 * 2048;

    f32x4 acc[8][4] = {};
    gemm8_core<false>(Ab, Bb, lds, 16, acc);

    const int lane = threadIdx.x & 63, wv = threadIdx.x >> 6;
    const int wr = wv >> 2, wc = wv & 3, lr = lane & 15, kh = lane >> 4;

    #pragma unroll
    for (int i = 0; i < 8; ++i) {
        const int srow0 = m0 + wr * 128 + i * 16 + kh * 4;  // 4 consecutive s
        const int b = srow0 >> 10, s = srow0 & 1023;
        #pragma unroll
        for (int j = 0; j < 4; ++j) {
            const int dcol = n0 + wc * 64 + j * 16 + lr;
            const float bb = bv[dcol];
            u16x4 o;
            o[0] = f2bf(acc[i][j][0] + bb);
            o[1] = f2bf(acc[i][j][1] + bb);
            o[2] = f2bf(acc[i][j][2] + bb);
            o[3] = f2bf(acc[i][j][3] + bb);
            *(u16x4*)(Vtb + ((size_t)b << 20) + ((size_t)dcol << 10) + s) = o;
        }
    }
}

// ===========================================================================
// Round-2 verified kernels below (conversion, scores, softmax, PV).
// ===========================================================================
__device__ __forceinline__ void mfma_core128(
    const unsigned short* __restrict__ Aa, const unsigned short* __restrict__ Bb,
    char* AsB, char* BsB, int kSteps, f32x4 acc[4][4])
{
    const int tid  = threadIdx.x;
    const int lane = tid & 63;
    const int wv   = tid >> 6;
    const int wr   = wv >> 1, wc = wv & 1;

    const int srow = wv * 16 + (lane >> 2);
    const int skb  = (lane & 3) * 16;

    const char* aS0 = (const char*)Aa + (size_t)srow * 2048 + skb;
    const char* aS1 = aS0 + 64 * 2048;
    const char* bS0 = (const char*)Bb + (size_t)srow * 2048 + skb;
    const char* bS1 = bS0 + 64 * 2048;
    char* aD0 = AsB + wv * 1024;  char* aD1 = aD0 + 4096;
    char* bD0 = BsB + wv * 1024;  char* bD1 = bD0 + 4096;

    const int lr = lane & 15, kh = lane >> 4;
    const char* aRd = AsB + (wr * 64 + lr) * 64 + kh * 16;
    const char* bRd = BsB + (wc * 64 + lr) * 64 + kh * 16;

    for (int ks = 0; ks < kSteps; ++ks) {
        gload_lds16(aS0, aD0);
        gload_lds16(aS1, aD1);
        gload_lds16(bS0, bD0);
        gload_lds16(bS1, bD1);
        aS0 += 64; aS1 += 64; bS0 += 64; bS1 += 64;
        __syncthreads();

        short8 af[4], bfr[4];
        #pragma unroll
        for (int i = 0; i < 4; ++i) af[i]  = *(const short8*)(aRd + i * 1024);
        #pragma unroll
        for (int j = 0; j < 4; ++j) bfr[j] = *(const short8*)(bRd + j * 1024);
        #pragma unroll
        for (int i = 0; i < 4; ++i)
            #pragma unroll
            for (int j = 0; j < 4; ++j)
                acc[i][j] = __builtin_amdgcn_mfma_f32_16x16x32_bf16(
                    af[i], bfr[j], acc[i][j], 0, 0, 0);
        __syncthreads();
    }
}

__global__ __launch_bounds__(256) void convert_bf16(
    const float* __restrict__ x,
    const float* __restrict__ Wq, const float* __restrict__ Wk,
    const float* __restrict__ Wv,
    unsigned short* __restrict__ Xb, unsigned short* __restrict__ Wb)
{
    const size_t NE  = (size_t)MTOT * EMB;
    const size_t idx = ((size_t)blockIdx.x * 256 + threadIdx.x) * 8;
    const float* src; unsigned short* dst; size_t off;
    if (idx < NE) { src = x; dst = Xb; off = idx; }
    else {
        const size_t w = idx - NE;
        const int wi = (int)(w >> 20);
        off = w & 0xFFFFFu;
        src = (wi == 0) ? Wq : (wi == 1) ? Wk : Wv;
        dst = Wb + ((size_t)wi << 20);
    }
    const float4 a = *(const float4*)(src + off);
    const float4 b = *(const float4*)(src + off + 4);
    u16x8 o;
    o[0] = f2bf(a.x); o[1] = f2bf(a.y); o[2] = f2bf(a.z); o[3] = f2bf(a.w);
    o[4] = f2bf(b.x); o[5] = f2bf(b.y); o[6] = f2bf(b.z); o[7] = f2bf(b.w);
    *(u16x8*)(dst + off) = o;
}

__global__ __launch_bounds__(256) void scores_mfma(
    const unsigned short* __restrict__ Qb, const unsigned short* __restrict__ Kb,
    float* __restrict__ sims)
{
    const int ti = blockIdx.x, tj = blockIdx.y, b = blockIdx.z;
    if (tj >= 2 && tj > ti) return;
    __shared__ __align__(16) char smem[16384];

    const size_t boff = (size_t)b << 20;
    const int m0 = ti * 128, n0 = tj * 128;
    const unsigned short* A = Qb + boff + (size_t)m0 * EMB;
    const unsigned short* B = Kb + boff + (size_t)n0 * EMB;
    f32x4 acc[4][4] = {};
    mfma_core128(A, B, smem, smem + 8192, EMB / 32, acc);

    float* S = sims + boff;
    const int tid = threadIdx.x, lane = tid & 63, wv = tid >> 6;
    const int wr = wv >> 1, wc = wv & 1, lr = lane & 15, kh = lane >> 4;
    #pragma unroll
    for (int i = 0; i < 4; ++i)
        #pragma unroll
        for (int j = 0; j < 4; ++j) {
            const int gcol = n0 + wc * 64 + j * 16 + lr;
            #pragma unroll
            for (int r = 0; r < 4; ++r) {
                const int grow = m0 + wr * 64 + i * 16 + kh * 4 + r;
                S[(size_t)grow * SEQL + gcol] = acc[i][j][r] * 0.03125f;
            }
        }
}

__global__ __launch_bounds__(256) void softmax_bf16(
    const float* __restrict__ sims, unsigned short* __restrict__ attnb)
{
    const int row = blockIdx.x;
    const int s   = row & (SEQL - 1);
    const int L   = (s + 1 > IMG) ? (s + 1) : IMG;
    const int Kt  = ((((s >> 7) + 1) << 7) > IMG) ? (((s >> 7) + 1) << 7) : IMG;

    const float* p = sims + (size_t)row * SEQL;
    const int tid = threadIdx.x, lane = tid & 63, wv = tid >> 6;
    const int c = tid * 4;
    const float4 v = *(const float4*)(p + c);

    __shared__ float red[8];

    float m = -3.0e38f;
    if (c + 0 < L) m = fmaxf(m, v.x);
    if (c + 1 < L) m = fmaxf(m, v.y);
    if (c + 2 < L) m = fmaxf(m, v.z);
    if (c + 3 < L) m = fmaxf(m, v.w);
    #pragma unroll
    for (int off = 32; off > 0; off >>= 1) m = fmaxf(m, __shfl_xor(m, off));
    if (lane == 0) red[wv] = m;
    __syncthreads();
    m = fmaxf(fmaxf(red[0], red[1]), fmaxf(red[2], red[3]));

    const float e0 = (c + 0 < L) ? __expf(v.x - m) : 0.0f;
    const float e1 = (c + 1 < L) ? __expf(v.y - m) : 0.0f;
    const float e2 = (c + 2 < L) ? __expf(v.z - m) : 0.0f;
    const float e3 = (c + 3 < L) ? __expf(v.w - m) : 0.0f;
    float ssum = e0 + e1 + e2 + e3;
    #pragma unroll
    for (int off = 32; off > 0; off >>= 1) ssum += __shfl_xor(ssum, off);
    if (lane == 0) red[4 + wv] = ssum;
    __syncthreads();
    const float inv = 1.0f / (red[4] + red[5] + red[6] + red[7]);

    if (c < Kt) {
        u16x4 o;
        o[0] = f2bf(e0 * inv); o[1] = f2bf(e1 * inv);
        o[2] = f2bf(e2 * inv); o[3] = f2bf(e3 * inv);
        *(u16x4*)(attnb + (size_t)row * SEQL + c) = o;
    }
}

__global__ __launch_bounds__(256) void pv_mfma(
    const unsigned short* __restrict__ attnb, const unsigned short* __restrict__ Vtb,
    float* __restrict__ out)
{
    const int ti = blockIdx.x, tj = blockIdx.y, b = blockIdx.z;
    __shared__ __align__(16) char smem[16384];

    const size_t boff = (size_t)b << 20;
    const int m0 = ti * 128, n0 = tj * 128;
    const int kmax = (m0 + 128 > IMG) ? (m0 + 128) : IMG;

    const unsigned short* A = attnb + boff + (size_t)m0 * SEQL;
    const unsigned short* B = Vtb + boff + (size_t)n0 * SEQL;
    f32x4 acc[4][4] = {};
    mfma_core128(A, B, smem, smem + 8192, kmax >> 5, acc);

    float* O = out + boff;
    const int tid = threadIdx.x, lane = tid & 63, wv = tid >> 6;
    const int wr = wv >> 1, wc = wv & 1, lr = lane & 15, kh = lane >> 4;
    #pragma unroll
    for (int i = 0; i < 4; ++i)
        #pragma unroll
        for (int j = 0; j < 4; ++j) {
            const int gcol = n0 + wc * 64 + j * 16 + lr;
            #pragma unroll
            for (int r = 0; r < 4; ++r) {
                const int grow = m0 + wr * 64 + i * 16 + kh * 4 + r;
                O[(size_t)grow * EMB + gcol] = acc[i][j][r];
            }
        }
}

// ---------------------------------------------------------------------------
extern "C" void kernel_launch(void* const* d_in, const int* in_sizes, int n_in,
                              void* d_out, int out_size, void* d_ws, size_t ws_size,
                              hipStream_t stream)
{
    const float* x  = (const float*)d_in[0];
    const float* Wq = (const float*)d_in[1];
    const float* bq = (const float*)d_in[2];
    const float* Wk = (const float*)d_in[3];
    const float* bk = (const float*)d_in[4];
    const float* Wv = (const float*)d_in[5];
    const float* bv = (const float*)d_in[6];

    const size_t NE = (size_t)MTOT * EMB;
    unsigned short* base  = (unsigned short*)d_ws;
    unsigned short* Qb    = base;                  // NE bf16
    unsigned short* Kb    = base + NE;             // NE
    unsigned short* Vtb   = base + 2 * NE;         // NE
    unsigned short* Xb    = base + 3 * NE;         // NE (dead after v_8phase)
    unsigned short* attnb = base + 3 * NE;         // reuses Xb region
    unsigned short* Wb    = base + 4 * NE;         // 3 * 2^20
    float* sims = (float*)d_out;

    // allow 128 KiB dynamic LDS for the 8-phase kernels
    hipFuncSetAttribute(reinterpret_cast<const void*>(qk_8phase),
                        hipFuncAttributeMaxDynamicSharedMemorySize, 131072);
    hipFuncSetAttribute(reinterpret_cast<const void*>(v_8phase),
                        hipFuncAttributeMaxDynamicSharedMemorySize, 131072);

    convert_bf16<<<dim3((unsigned)((NE + 3u * (1u << 20)) / 2048)), 256, 0, stream>>>(
        x, Wq, Wk, Wv, Xb, Wb);

    qk_8phase<<<dim3(MTOT / 256, EMB / 256, 2), 512, 131072, stream>>>(
        Xb, Wb, bq, bk, Qb, Kb);
    v_8phase<<<dim3(MTOT / 256, EMB / 256, 1), 512, 131072, stream>>>(
        Xb, Wb, bv, Vtb);

    scores_mfma<<<dim3(8, 8, BATCH), 256, 0, stream>>>(Qb, Kb, sims);

    softmax_bf16<<<dim3(MTOT), 256, 0, stream>>>(sims, attnb);

    pv_mfma<<<dim3(8, 8, BATCH), 256, 0, stream>>>(attnb, Vtb, (float*)d_out);
}

// Round 4
// 221.693 us; speedup vs baseline: 13.6596x; 1.1959x over previous
//
#include <hip/hip_runtime.h>
#include <hip/hip_bf16.h>
#include <stdint.h>

// Masked self-attention (round 4).
// All three GEMMs (qkv, scores, pv) on the 8-phase 256^2 MFMA core
// (T2 swizzle + T4 counted vmcnt + T5 setprio).  qkv merged into one z=3
// dispatch.  softmax zero-pads attn rows to 256-aligned boundaries so pv's
// truncated K-loop (KT=(ti+1)*4 tiles of BK=64) reads exact zeros.

#define BATCH 16
#define SEQL  1024
#define IMG   256
#define EMB   1024
#define MTOT  (BATCH * SEQL)   // 16384

typedef __attribute__((ext_vector_type(8))) short short8;
typedef __attribute__((ext_vector_type(8))) unsigned short u16x8;
typedef __attribute__((ext_vector_type(4))) unsigned short u16x4;
typedef __attribute__((ext_vector_type(4))) float f32x4;

__device__ __forceinline__ void gload_lds16(const void* g, void* l) {
    __builtin_amdgcn_global_load_lds(
        (const __attribute__((address_space(1))) void*)g,
        (__attribute__((address_space(3))) void*)l, 16, 0, 0);
}

__device__ __forceinline__ unsigned short f2bf(float f) {
    uint32_t u = __float_as_uint(f);
    u += 0x7FFFu + ((u >> 16) & 1u);
    return (unsigned short)(u >> 16);
}

// ===========================================================================
// 8-phase 256x256 GEMM core (verified round 3).  C = A(256 x 64*KT) * B^T,
// A/B row-major, row stride 2048 B.  8 waves (2M x 4N), wave tile 128x64,
// acc[8][4] f32x4.  LDS 128 KiB double-buffered, XOR-swizzled (st_16x32-style
// via pre-swizzled gload source + swizzled ds_read).  Counted vmcnt(2) at
// tile boundary only; raw s_barrier; setprio around MFMA clusters.
// SWAP=true computes mfma(B,A): C-frag row index = lane&15 (M), col index =
// (lane>>4)*4+r (N) -> packed stores along N.
// ===========================================================================
template<bool SWAP>
__device__ __forceinline__ void gemm8_core(
    const char* __restrict__ Ab, const char* __restrict__ Bb,
    char* lds, const int KT, f32x4 acc[8][4])
{
    const int tid  = threadIdx.x;
    const int lane = tid & 63;
    const int wv   = tid >> 6;
    const int wr   = wv >> 2, wc = wv & 3;
    const int lr   = lane & 15, kh = lane >> 4;

    const int sw  = (lr & 7) << 4;
    const int cb0 = (kh * 16) ^ sw;
    const int cb1 = (64 + kh * 16) ^ sw;

    const size_t psStage = (size_t)(wv * 16 + (lane >> 3)) * 2048
                         + (size_t)((((lane & 7) ^ (lane >> 3))) << 4);

    auto stageA = [&](int tt, int h) {
        if (tt < KT) {
            const char* s = Ab + psStage + (size_t)h * 262144 + (size_t)tt * 128;
            char* d = lds + (tt & 1) * 65536 + h * 16384 + wv * 2048;
            gload_lds16(s, d);
            gload_lds16(s + 16384, d + 1024);
        }
    };
    auto stageB = [&](int tt, int h) {
        if (tt < KT) {
            const char* s = Bb + psStage + (size_t)h * 262144 + (size_t)tt * 128;
            char* d = lds + (tt & 1) * 65536 + 32768 + h * 16384 + wv * 2048;
            gload_lds16(s, d);
            gload_lds16(s + 16384, d + 1024);
        }
    };

    stageA(0, 0); stageA(0, 1); stageB(0, 0); stageB(0, 1); stageA(1, 0);
    asm volatile("s_waitcnt vmcnt(2)" ::: "memory");
    __builtin_amdgcn_s_barrier();

    short8 af[4][2];
    short8 bf[4][2];

    const int bh   = wc >> 1;
    const int brow = (wc & 1) * 64 + lr;

    #pragma unroll 1
    for (int t = 0; t < KT; ++t) {
        const int d = t & 1;
        const char* aBase = lds + d * 65536 + wr * 16384 + lr * 128;
        const char* bBase = lds + d * 65536 + 32768 + bh * 16384 + brow * 128;

        auto loadA = [&](int IQ) {
            #pragma unroll
            for (int ii = 0; ii < 4; ++ii) {
                af[ii][0] = *(const short8*)(aBase + (IQ * 4 + ii) * 2048 + cb0);
                af[ii][1] = *(const short8*)(aBase + (IQ * 4 + ii) * 2048 + cb1);
            }
        };
        auto loadB = [&](int JQ) {
            #pragma unroll
            for (int jj = 0; jj < 2; ++jj) {
                bf[JQ * 2 + jj][0] = *(const short8*)(bBase + (JQ * 2 + jj) * 2048 + cb0);
                bf[JQ * 2 + jj][1] = *(const short8*)(bBase + (JQ * 2 + jj) * 2048 + cb1);
            }
        };
        auto mfma16 = [&](int IQ, int JQ) {
            __builtin_amdgcn_s_barrier();
            __builtin_amdgcn_s_setprio(1);
            #pragma unroll
            for (int ii = 0; ii < 4; ++ii)
                #pragma unroll
                for (int jj = 0; jj < 2; ++jj)
                    #pragma unroll
                    for (int kk = 0; kk < 2; ++kk) {
                        f32x4& c = acc[IQ * 4 + ii][JQ * 2 + jj];
                        if (SWAP)
                            c = __builtin_amdgcn_mfma_f32_16x16x32_bf16(
                                bf[JQ * 2 + jj][kk], af[ii][kk], c, 0, 0, 0);
                        else
                            c = __builtin_amdgcn_mfma_f32_16x16x32_bf16(
                                af[ii][kk], bf[JQ * 2 + jj][kk], c, 0, 0, 0);
                    }
            __builtin_amdgcn_s_setprio(0);
        };

        loadA(0); loadB(0); stageA(t + 1, 1);
        mfma16(0, 0);
        __builtin_amdgcn_s_barrier();
        loadB(1); stageB(t + 1, 0);
        mfma16(0, 1);
        __builtin_amdgcn_s_barrier();
        loadA(1); stageB(t + 1, 1);
        mfma16(1, 1);
        __builtin_amdgcn_s_barrier();
        stageA(t + 2, 0);
        mfma16(1, 0);
        if (t < KT - 2) asm volatile("s_waitcnt vmcnt(2)" ::: "memory");
        else            asm volatile("s_waitcnt vmcnt(0)" ::: "memory");
        __builtin_amdgcn_s_barrier();
    }
}

// ---------------------------------------------------------------------------
// QKV projection, one dispatch: z=0 -> Qb, z=1 -> Kb (row-major bf16, SWAP
// epilogue, packed 8 B stores), z=2 -> Vtb transposed [b][d][s] (non-SWAP,
// packed 8 B stores along s).
// ---------------------------------------------------------------------------
__global__ void __launch_bounds__(512, 1) qkv_8phase(
    const unsigned short* __restrict__ Xb, const unsigned short* __restrict__ Wb,
    const float* __restrict__ bq, const float* __restrict__ bk,
    const float* __restrict__ bv,
    unsigned short* __restrict__ Qb, unsigned short* __restrict__ Kb,
    unsigned short* __restrict__ Vtb)
{
    extern __shared__ char lds[];
    const int m0 = blockIdx.x * 256, n0 = blockIdx.y * 256, z = blockIdx.z;
    const char* Ab = (const char*)Xb + (size_t)m0 * 2048;
    const char* Bb = (const char*)(Wb + ((size_t)z << 20)) + (size_t)n0 * 2048;

    const int lane = threadIdx.x & 63, wv = threadIdx.x >> 6;
    const int wr = wv >> 2, wc = wv & 3, lr = lane & 15, kh = lane >> 4;

    if (z < 2) {
        f32x4 acc[8][4] = {};
        gemm8_core<true>(Ab, Bb, lds, 16, acc);

        unsigned short* Y = z ? Kb : Qb;
        const float* bias = z ? bk : bq;
        #pragma unroll
        for (int i = 0; i < 8; ++i) {
            const int grow = m0 + wr * 128 + i * 16 + lr;
            #pragma unroll
            for (int j = 0; j < 4; ++j) {
                const int gc0 = n0 + wc * 64 + j * 16 + kh * 4;
                const float4 bb = *(const float4*)(bias + gc0);
                u16x4 o;
                o[0] = f2bf(acc[i][j][0] + bb.x);
                o[1] = f2bf(acc[i][j][1] + bb.y);
                o[2] = f2bf(acc[i][j][2] + bb.z);
                o[3] = f2bf(acc[i][j][3] + bb.w);
                *(u16x4*)(Y + (size_t)grow * EMB + gc0) = o;
            }
        }
    } else {
        f32x4 acc[8][4] = {};
        gemm8_core<false>(Ab, Bb, lds, 16, acc);

        #pragma unroll
        for (int i = 0; i < 8; ++i) {
            const int srow0 = m0 + wr * 128 + i * 16 + kh * 4;
            const int b = srow0 >> 10, s = srow0 & 1023;
            #pragma unroll
            for (int j = 0; j < 4; ++j) {
                const int dcol = n0 + wc * 64 + j * 16 + lr;
                const float bb = bv[dcol];
                u16x4 o;
                o[0] = f2bf(acc[i][j][0] + bb);
                o[1] = f2bf(acc[i][j][1] + bb);
                o[2] = f2bf(acc[i][j][2] + bb);
                o[3] = f2bf(acc[i][j][3] + bb);
                *(u16x4*)(Vtb + ((size_t)b << 20) + ((size_t)dcol << 10) + s) = o;
            }
        }
    }
}

// ---------------------------------------------------------------------------
// scores[b,q,k] = (Q.K)/32 fp32, 256^2 tiles, skip fully-masked (tj>ti).
// SWAP epilogue: packed float4 stores along k.
// ---------------------------------------------------------------------------
__global__ void __launch_bounds__(512, 1) scores_8ph(
    const unsigned short* __restrict__ Qb, const unsigned short* __restrict__ Kb,
    float* __restrict__ sims)
{
    const int ti = blockIdx.x, tj = blockIdx.y, b = blockIdx.z;
    if (tj > ti) return;
    extern __shared__ char lds[];

    const size_t boff = (size_t)b << 20;
    const int m0 = ti * 256, n0 = tj * 256;
    const char* Ab = (const char*)(Qb + boff) + (size_t)m0 * 2048;
    const char* Bb = (const char*)(Kb + boff) + (size_t)n0 * 2048;

    f32x4 acc[8][4] = {};
    gemm8_core<true>(Ab, Bb, lds, 16, acc);

    float* S = sims + boff;
    const int lane = threadIdx.x & 63, wv = threadIdx.x >> 6;
    const int wr = wv >> 2, wc = wv & 3, lr = lane & 15, kh = lane >> 4;
    #pragma unroll
    for (int i = 0; i < 8; ++i) {
        const int q = m0 + wr * 128 + i * 16 + lr;
        #pragma unroll
        for (int j = 0; j < 4; ++j) {
            const int k0 = n0 + wc * 64 + j * 16 + kh * 4;
            float4 o;
            o.x = acc[i][j][0] * 0.03125f;
            o.y = acc[i][j][1] * 0.03125f;
            o.z = acc[i][j][2] * 0.03125f;
            o.w = acc[i][j][3] * 0.03125f;
            *(float4*)(S + (size_t)q * SEQL + k0) = o;
        }
    }
}

// ---------------------------------------------------------------------------
// Row softmax over valid prefix L = max(256, s+1); bf16 out zero-padded to
// Kt = max(256, 256*(s/256+1)) — matches pv's 256-wide K truncation.
// ---------------------------------------------------------------------------
__global__ __launch_bounds__(256) void softmax_bf16(
    const float* __restrict__ sims, unsigned short* __restrict__ attnb)
{
    const int row = blockIdx.x;
    const int s   = row & (SEQL - 1);
    const int L   = (s + 1 > IMG) ? (s + 1) : IMG;
    const int Kt  = ((((s >> 8) + 1) << 8) > IMG) ? (((s >> 8) + 1) << 8) : IMG;

    const float* p = sims + (size_t)row * SEQL;
    const int tid = threadIdx.x, lane = tid & 63, wv = tid >> 6;
    const int c = tid * 4;
    const float4 v = *(const float4*)(p + c);

    __shared__ float red[8];

    float m = -3.0e38f;
    if (c + 0 < L) m = fmaxf(m, v.x);
    if (c + 1 < L) m = fmaxf(m, v.y);
    if (c + 2 < L) m = fmaxf(m, v.z);
    if (c + 3 < L) m = fmaxf(m, v.w);
    #pragma unroll
    for (int off = 32; off > 0; off >>= 1) m = fmaxf(m, __shfl_xor(m, off));
    if (lane == 0) red[wv] = m;
    __syncthreads();
    m = fmaxf(fmaxf(red[0], red[1]), fmaxf(red[2], red[3]));

    const float e0 = (c + 0 < L) ? __expf(v.x - m) : 0.0f;
    const float e1 = (c + 1 < L) ? __expf(v.y - m) : 0.0f;
    const float e2 = (c + 2 < L) ? __expf(v.z - m) : 0.0f;
    const float e3 = (c + 3 < L) ? __expf(v.w - m) : 0.0f;
    float ssum = e0 + e1 + e2 + e3;
    #pragma unroll
    for (int off = 32; off > 0; off >>= 1) ssum += __shfl_xor(ssum, off);
    if (lane == 0) red[4 + wv] = ssum;
    __syncthreads();
    const float inv = 1.0f / (red[4] + red[5] + red[6] + red[7]);

    if (c < Kt) {
        u16x4 o;
        o[0] = f2bf(e0 * inv); o[1] = f2bf(e1 * inv);
        o[2] = f2bf(e2 * inv); o[3] = f2bf(e3 * inv);
        *(u16x4*)(attnb + (size_t)row * SEQL + c) = o;
    }
}

// ---------------------------------------------------------------------------
// out[b,q,d] = attn[b,q,:] . V[b,:,d] via B^T GEMM against Vt[b][d][k].
// 256^2 tiles, KT = (ti+1)*4 K-tiles of 64.  SWAP epilogue: packed float4.
// ---------------------------------------------------------------------------
__global__ void __launch_bounds__(512, 1) pv_8ph(
    const unsigned short* __restrict__ attnb, const unsigned short* __restrict__ Vtb,
    float* __restrict__ out)
{
    const int ti = blockIdx.x, tj = blockIdx.y, b = blockIdx.z;
    extern __shared__ char lds[];

    const size_t boff = (size_t)b << 20;
    const int m0 = ti * 256, n0 = tj * 256;
    const int KT = (ti + 1) * 4;   // kmax = max(256, m0+256) = (ti+1)*256

    const char* Ab = (const char*)(attnb + boff) + (size_t)m0 * 2048;
    const char* Bb = (const char*)(Vtb + boff) + (size_t)n0 * 2048;

    f32x4 acc[8][4] = {};
    gemm8_core<true>(Ab, Bb, lds, KT, acc);

    float* O = out + boff;
    const int lane = threadIdx.x & 63, wv = threadIdx.x >> 6;
    const int wr = wv >> 2, wc = wv & 3, lr = lane & 15, kh = lane >> 4;
    #pragma unroll
    for (int i = 0; i < 8; ++i) {
        const int q = m0 + wr * 128 + i * 16 + lr;
        #pragma unroll
        for (int j = 0; j < 4; ++j) {
            const int d0 = n0 + wc * 64 + j * 16 + kh * 4;
            *(float4*)(O + (size_t)q * EMB + d0) = *(const float4*)&acc[i][j];
        }
    }
}

// ---------------------------------------------------------------------------
// fp32 -> bf16 conversion of x and the three weight matrices.
// ---------------------------------------------------------------------------
__global__ __launch_bounds__(256) void convert_bf16(
    const float* __restrict__ x,
    const float* __restrict__ Wq, const float* __restrict__ Wk,
    const float* __restrict__ Wv,
    unsigned short* __restrict__ Xb, unsigned short* __restrict__ Wb)
{
    const size_t NE  = (size_t)MTOT * EMB;
    const size_t idx = ((size_t)blockIdx.x * 256 + threadIdx.x) * 8;
    const float* src; unsigned short* dst; size_t off;
    if (idx < NE) { src = x; dst = Xb; off = idx; }
    else {
        const size_t w = idx - NE;
        const int wi = (int)(w >> 20);
        off = w & 0xFFFFFu;
        src = (wi == 0) ? Wq : (wi == 1) ? Wk : Wv;
        dst = Wb + ((size_t)wi << 20);
    }
    const float4 a = *(const float4*)(src + off);
    const float4 b = *(const float4*)(src + off + 4);
    u16x8 o;
    o[0] = f2bf(a.x); o[1] = f2bf(a.y); o[2] = f2bf(a.z); o[3] = f2bf(a.w);
    o[4] = f2bf(b.x); o[5] = f2bf(b.y); o[6] = f2bf(b.z); o[7] = f2bf(b.w);
    *(u16x8*)(dst + off) = o;
}

// ---------------------------------------------------------------------------
extern "C" void kernel_launch(void* const* d_in, const int* in_sizes, int n_in,
                              void* d_out, int out_size, void* d_ws, size_t ws_size,
                              hipStream_t stream)
{
    const float* x  = (const float*)d_in[0];
    const float* Wq = (const float*)d_in[1];
    const float* bq = (const float*)d_in[2];
    const float* Wk = (const float*)d_in[3];
    const float* bk = (const float*)d_in[4];
    const float* Wv = (const float*)d_in[5];
    const float* bv = (const float*)d_in[6];

    const size_t NE = (size_t)MTOT * EMB;
    unsigned short* base  = (unsigned short*)d_ws;
    unsigned short* Qb    = base;                  // NE bf16
    unsigned short* Kb    = base + NE;             // NE
    unsigned short* Vtb   = base + 2 * NE;         // NE
    unsigned short* Xb    = base + 3 * NE;         // NE (dead after qkv)
    unsigned short* attnb = base + 3 * NE;         // reuses Xb region
    unsigned short* Wb    = base + 4 * NE;         // 3 * 2^20
    float* sims = (float*)d_out;

    hipFuncSetAttribute(reinterpret_cast<const void*>(qkv_8phase),
                        hipFuncAttributeMaxDynamicSharedMemorySize, 131072);
    hipFuncSetAttribute(reinterpret_cast<const void*>(scores_8ph),
                        hipFuncAttributeMaxDynamicSharedMemorySize, 131072);
    hipFuncSetAttribute(reinterpret_cast<const void*>(pv_8ph),
                        hipFuncAttributeMaxDynamicSharedMemorySize, 131072);

    convert_bf16<<<dim3((unsigned)((NE + 3u * (1u << 20)) / 2048)), 256, 0, stream>>>(
        x, Wq, Wk, Wv, Xb, Wb);

    qkv_8phase<<<dim3(MTOT / 256, EMB / 256, 3), 512, 131072, stream>>>(
        Xb, Wb, bq, bk, bv, Qb, Kb, Vtb);

    scores_8ph<<<dim3(4, 4, BATCH), 512, 131072, stream>>>(Qb, Kb, sims);

    softmax_bf16<<<dim3(MTOT), 256, 0, stream>>>(sims, attnb);

    pv_8ph<<<dim3(4, 4, BATCH), 512, 131072, stream>>>(attnb, Vtb, (float*)d_out);
}